// Round 1
// baseline (573.509 us; speedup 1.0000x reference)
//
#include <hip/hip_runtime.h>
#include <math.h>

#define BB 2
#define LL 1024
#define EE 512
#define HH 8
#define DD 64
#define NROWS (BB*LL)   // 2048

// C = X @ W^T + bias.  X:[2048][512], W:[512][512] row-major.
// mode 0: out[m*512+n] (natural)
// mode 1: K-transposed: out[(b*512 + n)*1024 + l]  (i.e. KT[b][h][d][l])
__global__ __launch_bounds__(256) void proj_gemm(const float* __restrict__ X,
                                                 const float* __restrict__ W,
                                                 const float* __restrict__ bias,
                                                 float* __restrict__ out,
                                                 int mode)
{
    __shared__ float Xs[64][33];
    __shared__ float Ws[64][33];
    const int tid = threadIdx.x;
    const int tx = tid & 15, ty = tid >> 4;
    const int m0 = blockIdx.x * 64, n0 = blockIdx.y * 64;
    float acc[4][4] = {};

    for (int kk = 0; kk < EE; kk += 32) {
        #pragma unroll
        for (int i = 0; i < 8; ++i) {
            int idx = i * 256 + tid;
            int r = idx >> 5, c = idx & 31;
            Xs[r][c] = X[(size_t)(m0 + r) * EE + kk + c];
            Ws[r][c] = W[(size_t)(n0 + r) * EE + kk + c];
        }
        __syncthreads();
        #pragma unroll
        for (int c = 0; c < 32; ++c) {
            float a[4], w[4];
            #pragma unroll
            for (int j = 0; j < 4; ++j) a[j] = Xs[ty * 4 + j][c];
            #pragma unroll
            for (int i = 0; i < 4; ++i) w[i] = Ws[tx * 4 + i][c];
            #pragma unroll
            for (int j = 0; j < 4; ++j)
                #pragma unroll
                for (int i = 0; i < 4; ++i)
                    acc[j][i] += a[j] * w[i];
        }
        __syncthreads();
    }

    #pragma unroll
    for (int j = 0; j < 4; ++j) {
        int m = m0 + ty * 4 + j;
        #pragma unroll
        for (int i = 0; i < 4; ++i) {
            int n = n0 + tx * 4 + i;
            float v = acc[j][i] + bias[n];
            if (mode == 1) {
                int b = m >> 10, l = m & 1023;
                out[(size_t)(b * 512 + n) * 1024 + l] = v;
            } else {
                out[(size_t)m * EE + n] = v;
            }
        }
    }
}

// One block (256 thr = 4 waves) per (b,q).
// Q: [B][L][E] natural, KT: [B][H][D][L], V: [B][L][E] natural.
// ATT out: [B][L][E].
__global__ __launch_bounds__(256) void attn_kernel(const float* __restrict__ Q,
                                                   const float* __restrict__ KT,
                                                   const float* __restrict__ V,
                                                   float* __restrict__ ATT)
{
    const int bq = blockIdx.x;            // 0..2047
    const int b = bq >> 10;
    const int tid = threadIdx.x;
    const int wave = tid >> 6, lane = tid & 63;

    __shared__ float qs[EE];
    __shared__ float s_lds[HH][64];
    __shared__ float inv_lds[64];
    __shared__ float outP[4][HH][64];

    for (int i = tid; i < EE; i += 256) qs[i] = Q[(size_t)bq * EE + i];

    float oacc[HH];
    #pragma unroll
    for (int h = 0; h < HH; ++h) oacc[h] = 0.f;

    const float scale = 0.125f;  // 1/sqrt(64)

    for (int k0 = 0; k0 < LL; k0 += 64) {
        __syncthreads();  // protects s_lds/inv_lds from previous tile's readers
        // ---- phase 1: scores s[h][k0+lane] for heads {wave, wave+4} ----
        #pragma unroll
        for (int hh = 0; hh < 2; ++hh) {
            int h = wave + hh * 4;
            const float* kp = KT + ((size_t)(b * HH + h) * DD) * LL + k0 + lane;
            float acc = 0.f;
            #pragma unroll 8
            for (int d = 0; d < DD; ++d)
                acc += qs[h * DD + d] * kp[(size_t)d * LL];
            s_lds[h][lane] = acc * scale;
        }
        __syncthreads();
        // ---- phase 2: inverse RMS over heads, per k ----
        if (tid < 64) {
            float ss = 0.f;
            #pragma unroll
            for (int h = 0; h < HH; ++h) { float x = s_lds[h][tid]; ss += x * x; }
            inv_lds[tid] = rsqrtf(ss * (1.0f / HH) + 1e-8f);
        }
        __syncthreads();
        // ---- phase 3: x = silu(sum_h w*v); out[h][lane] += w*x ----
        for (int kk = 0; kk < 16; ++kk) {
            int kloc = wave * 16 + kk;
            int k = k0 + kloc;
            float inv = inv_lds[kloc];
            float wv[HH];
            #pragma unroll
            for (int h = 0; h < HH; ++h) wv[h] = s_lds[h][kloc] * inv;
            const float* vp = V + ((size_t)(b * LL + k)) * EE + lane;
            float xv = 0.f;
            #pragma unroll
            for (int h = 0; h < HH; ++h) xv += wv[h] * vp[h * DD];
            xv = xv / (1.f + __expf(-xv));   // silu
            #pragma unroll
            for (int h = 0; h < HH; ++h) oacc[h] += wv[h] * xv;
        }
    }

    #pragma unroll
    for (int h = 0; h < HH; ++h) outP[wave][h][lane] = oacc[h];
    __syncthreads();
    for (int e = tid; e < EE; e += 256) {
        int h = e >> 6, d = e & 63;
        float v = outP[0][h][d] + outP[1][h][d] + outP[2][h][d] + outP[3][h][d];
        ATT[(size_t)bq * EE + e] = v;
    }
}

extern "C" void kernel_launch(void* const* d_in, const int* in_sizes, int n_in,
                              void* d_out, int out_size, void* d_ws, size_t ws_size,
                              hipStream_t stream) {
    const float* query = (const float*)d_in[0];
    const float* key   = (const float*)d_in[1];
    const float* value = (const float*)d_in[2];
    const float* Wq = (const float*)d_in[3];
    const float* bq = (const float*)d_in[4];
    const float* Wk = (const float*)d_in[5];
    const float* bk = (const float*)d_in[6];
    const float* Wv = (const float*)d_in[7];
    const float* bv = (const float*)d_in[8];
    const float* Wo = (const float*)d_in[9];
    const float* bo = (const float*)d_in[10];
    float* out = (float*)d_out;

    float* ws = (float*)d_ws;
    const size_t SZ = (size_t)NROWS * EE;   // 1M floats
    float* Qb  = ws;
    float* KTb = ws + SZ;
    float* Vb  = ws + 2 * SZ;
    float* ATT = ws + 3 * SZ;

    dim3 gG(NROWS / 64, EE / 64, 1);
    dim3 bG(256, 1, 1);

    proj_gemm<<<gG, bG, 0, stream>>>(query, Wq, bq, Qb, 0);
    proj_gemm<<<gG, bG, 0, stream>>>(key,   Wk, bk, KTb, 1);
    proj_gemm<<<gG, bG, 0, stream>>>(value, Wv, bv, Vb, 0);

    attn_kernel<<<dim3(NROWS, 1, 1), bG, 0, stream>>>(Qb, KTb, Vb, ATT);

    proj_gemm<<<gG, bG, 0, stream>>>(ATT, Wo, bo, out, 0);
}

// Round 2
// 383.058 us; speedup vs baseline: 1.4972x; 1.4972x over previous
//
#include <hip/hip_runtime.h>
#include <hip/hip_bf16.h>
#include <math.h>

#define BB 2
#define LL 1024
#define EE 512
#define HH 8
#define DD 64
#define NROWS (BB*LL)   // 2048
#define QT 8
#define KSPLIT 4
#define KRANGE (LL/KSPLIT)  // 256

typedef __attribute__((ext_vector_type(4))) float f32x4;
typedef __attribute__((ext_vector_type(8))) short short8;

static __device__ __forceinline__ short to_bf16(float f) {
    __bf16 h = (__bf16)f;
    return __builtin_bit_cast(short, h);
}

// ---------------- bf16 MFMA GEMM: out = X @ W^T + bias ----------------
// X: [2048][512] f32, W: [512][512] f32 (row-major; we need W rows = B^T input).
// MODE 0: out[m*512+n].  MODE 1: out[(b*512+n)*1024 + (m&1023)]  (KT layout).
template<int MODE>
__global__ __launch_bounds__(256) void gemm_bf16(const float* __restrict__ X,
                                                 const float* __restrict__ W,
                                                 const float* __restrict__ bias,
                                                 float* __restrict__ out)
{
    __shared__ short As[64 * 32];
    __shared__ short Bs[64 * 32];

    const int tid  = threadIdx.x;
    const int lane = tid & 63, wave = tid >> 6;
    const int wr = wave >> 1, wc = wave & 1;        // wave's 32x32 quadrant
    const int m0 = blockIdx.x * 64, n0 = blockIdx.y * 64;

    // staging map: thread -> (row r, 8-float chunk cq)
    const int r = tid >> 2, cq = tid & 3;
    const float* ax = X + (size_t)(m0 + r) * EE + cq * 8;
    const float* bx = W + (size_t)(n0 + r) * EE + cq * 8;

    float a_reg[8], b_reg[8];
    #pragma unroll
    for (int j = 0; j < 8; ++j) { a_reg[j] = ax[j]; b_reg[j] = bx[j]; }

    f32x4 acc[2][2];
    #pragma unroll
    for (int mi = 0; mi < 2; ++mi)
        #pragma unroll
        for (int ni = 0; ni < 2; ++ni)
            acc[mi][ni] = (f32x4){0.f, 0.f, 0.f, 0.f};

    short* apos = &As[r * 32 + ((cq ^ (r & 3)) * 8)];   // XOR chunk swizzle
    short* bpos = &Bs[r * 32 + ((cq ^ (r & 3)) * 8)];
    const int ks = lane >> 4;
    const int swz = (ks ^ (lane & 3)) * 8;              // row&3 == lane&3 for all frags

    for (int it = 0; it < 16; ++it) {
        short8 av, bv;
        #pragma unroll
        for (int j = 0; j < 8; ++j) { av[j] = to_bf16(a_reg[j]); bv[j] = to_bf16(b_reg[j]); }
        __syncthreads();
        *reinterpret_cast<short8*>(apos) = av;
        *reinterpret_cast<short8*>(bpos) = bv;
        __syncthreads();
        if (it < 15) {
            const float* axn = ax + (it + 1) * 32;
            const float* bxn = bx + (it + 1) * 32;
            #pragma unroll
            for (int j = 0; j < 8; ++j) { a_reg[j] = axn[j]; b_reg[j] = bxn[j]; }
        }
        short8 af[2], bf[2];
        #pragma unroll
        for (int mi = 0; mi < 2; ++mi) {
            int row = wr * 32 + mi * 16 + (lane & 15);
            af[mi] = *reinterpret_cast<short8*>(&As[row * 32 + swz]);
        }
        #pragma unroll
        for (int ni = 0; ni < 2; ++ni) {
            int row = wc * 32 + ni * 16 + (lane & 15);
            bf[ni] = *reinterpret_cast<short8*>(&Bs[row * 32 + swz]);
        }
        #pragma unroll
        for (int mi = 0; mi < 2; ++mi)
            #pragma unroll
            for (int ni = 0; ni < 2; ++ni)
                acc[mi][ni] = __builtin_amdgcn_mfma_f32_16x16x32_bf16(af[mi], bf[ni], acc[mi][ni], 0, 0, 0);
    }

    const int col_l = lane & 15, rowg = (lane >> 4) * 4;
    if constexpr (MODE == 0) {
        #pragma unroll
        for (int mi = 0; mi < 2; ++mi)
            #pragma unroll
            for (int ni = 0; ni < 2; ++ni) {
                int colg = n0 + wc * 32 + ni * 16 + col_l;
                float bn = bias[colg];
                #pragma unroll
                for (int rr = 0; rr < 4; ++rr) {
                    int mg = m0 + wr * 32 + mi * 16 + rowg + rr;
                    out[(size_t)mg * EE + colg] = acc[mi][ni][rr] + bn;
                }
            }
    } else {
        __shared__ float Cs[64 * 65];
        #pragma unroll
        for (int mi = 0; mi < 2; ++mi)
            #pragma unroll
            for (int ni = 0; ni < 2; ++ni) {
                int cl = wc * 32 + ni * 16 + col_l;
                float bn = bias[n0 + cl];
                #pragma unroll
                for (int rr = 0; rr < 4; ++rr) {
                    int ml = wr * 32 + mi * 16 + rowg + rr;
                    Cs[cl * 65 + ml] = acc[mi][ni][rr] + bn;
                }
            }
        __syncthreads();
        for (int i = tid; i < 4096; i += 256) {
            int cl = i >> 6, ml = i & 63;
            int mg = m0 + ml;
            int b = mg >> 10, l = mg & 1023;
            out[((size_t)(b * EE + n0 + cl)) * LL + l] = Cs[cl * 65 + ml];
        }
    }
}

// ---------------- fused attention (q-tiled, k-split) ----------------
// Q:[B][L][E], KT:[B][H][D][L], V:[B][L][E]. ATT accumulated via atomicAdd.
__global__ __launch_bounds__(256, 4) void attn2(const float* __restrict__ Q,
                                                const float* __restrict__ KT,
                                                const float* __restrict__ V,
                                                float* __restrict__ ATT)
{
    __shared__ float qsT[EE * QT];      // [e][q]  16 KB
    __shared__ float sw[QT * HH * 64];  // [q][h][k] 16 KB (reused as reduce buf)

    const int tid = threadIdx.x, lane = tid & 63, wave = tid >> 6;
    const int bq0 = blockIdx.x * QT;
    const int b = bq0 >> 10;
    const int ksp = blockIdx.y;

    for (int i = tid; i < QT * EE; i += 256) {
        int q = i >> 9, e = i & 511;
        qsT[e * QT + q] = Q[(size_t)(bq0 + q) * EE + e];
    }

    float oacc[QT][HH];
    #pragma unroll
    for (int q = 0; q < QT; ++q)
        #pragma unroll
        for (int h = 0; h < HH; ++h) oacc[q][h] = 0.f;

    for (int t = 0; t < KRANGE / 64; ++t) {
        const int k0 = ksp * KRANGE + t * 64;
        __syncthreads();   // prev phase-3 readers done; qsT ready (t==0)

        // ---- phase 1: scores, wave computes heads {wave, wave+4}, lane = k ----
        #pragma unroll
        for (int hh = 0; hh < 2; ++hh) {
            const int h = wave + hh * 4;
            const float* kp = KT + ((size_t)(b * EE + h * DD)) * LL + k0 + lane;
            const float* qp = &qsT[(h * DD) * QT];
            float acc[QT];
            #pragma unroll
            for (int q = 0; q < QT; ++q) acc[q] = 0.f;
            #pragma unroll 4
            for (int d = 0; d < DD; ++d) {
                float kv = kp[(size_t)d * LL];
                f32x4 q03 = *reinterpret_cast<const f32x4*>(&qp[d * QT]);
                f32x4 q47 = *reinterpret_cast<const f32x4*>(&qp[d * QT + 4]);
                #pragma unroll
                for (int j = 0; j < 4; ++j) { acc[j] += q03[j] * kv; acc[4 + j] += q47[j] * kv; }
            }
            #pragma unroll
            for (int q = 0; q < QT; ++q)
                sw[(q * HH + h) * 64 + lane] = acc[q] * 0.125f;
        }
        __syncthreads();

        // ---- phase 2: RMS over heads, normalize in place ----
        #pragma unroll
        for (int i2 = 0; i2 < 2; ++i2) {
            int p = tid + i2 * 256;
            int q = p >> 6, kl = p & 63;
            float* sp = &sw[(q * HH) * 64 + kl];
            float vv[HH], ssum = 0.f;
            #pragma unroll
            for (int h = 0; h < HH; ++h) { vv[h] = sp[h * 64]; ssum += vv[h] * vv[h]; }
            float inv = rsqrtf(ssum * 0.125f + 1e-8f);
            #pragma unroll
            for (int h = 0; h < HH; ++h) sp[h * 64] = vv[h] * inv;
        }
        __syncthreads();

        // ---- phase 3: waves interleave k; V row loaded once, reused by 8 q ----
        for (int j = 0; j < 16; ++j) {
            int kl = j * 4 + wave;
            int kg = k0 + kl;
            const float* vp = V + (size_t)(b * LL + kg) * EE + lane;
            float vreg[HH];
            #pragma unroll
            for (int h = 0; h < HH; ++h) vreg[h] = vp[h * DD];
            #pragma unroll
            for (int q = 0; q < QT; ++q) {
                const float* sp = &sw[(q * HH) * 64 + kl];
                float w[HH], xv = 0.f;
                #pragma unroll
                for (int h = 0; h < HH; ++h) { w[h] = sp[h * 64]; xv += w[h] * vreg[h]; }
                float sx = xv / (1.f + __expf(-xv));
                #pragma unroll
                for (int h = 0; h < HH; ++h) oacc[q][h] += w[h] * sx;
            }
        }
    }

    // ---- cross-wave reduce + global accumulate ----
    float* red = sw;
    #pragma unroll
    for (int q = 0; q < QT; ++q) {
        __syncthreads();
        #pragma unroll
        for (int h = 0; h < HH; ++h) red[(wave * HH + h) * 64 + lane] = oacc[q][h];
        __syncthreads();
        #pragma unroll
        for (int i2 = 0; i2 < 2; ++i2) {
            int e = tid + i2 * 256;
            float sum = red[e] + red[e + 512] + red[e + 1024] + red[e + 1536];
            atomicAdd(&ATT[(size_t)(bq0 + q) * EE + e], sum);
        }
    }
}

extern "C" void kernel_launch(void* const* d_in, const int* in_sizes, int n_in,
                              void* d_out, int out_size, void* d_ws, size_t ws_size,
                              hipStream_t stream) {
    const float* query = (const float*)d_in[0];
    const float* key   = (const float*)d_in[1];
    const float* value = (const float*)d_in[2];
    const float* Wq = (const float*)d_in[3];
    const float* biasq = (const float*)d_in[4];
    const float* Wk = (const float*)d_in[5];
    const float* biask = (const float*)d_in[6];
    const float* Wv = (const float*)d_in[7];
    const float* biasv = (const float*)d_in[8];
    const float* Wo = (const float*)d_in[9];
    const float* biaso = (const float*)d_in[10];
    float* out = (float*)d_out;

    float* ws = (float*)d_ws;
    const size_t SZ = (size_t)NROWS * EE;   // 1M floats
    float* Qb  = ws;
    float* KTb = ws + SZ;
    float* Vb  = ws + 2 * SZ;
    float* ATT = ws + 3 * SZ;

    hipMemsetAsync(ATT, 0, SZ * sizeof(float), stream);

    dim3 gG(NROWS / 64, EE / 64, 1);
    gemm_bf16<0><<<gG, 256, 0, stream>>>(query, Wq, biasq, Qb);
    gemm_bf16<1><<<gG, 256, 0, stream>>>(key,   Wk, biask, KTb);
    gemm_bf16<0><<<gG, 256, 0, stream>>>(value, Wv, biasv, Vb);

    attn2<<<dim3(NROWS / QT, KSPLIT, 1), dim3(256, 1, 1), 0, stream>>>(Qb, KTb, Vb, ATT);

    gemm_bf16<0><<<gG, 256, 0, stream>>>(ATT, Wo, biaso, out);
}

// Round 3
// 246.352 us; speedup vs baseline: 2.3280x; 1.5549x over previous
//
#include <hip/hip_runtime.h>
#include <hip/hip_bf16.h>
#include <math.h>

#define BB 2
#define LL 1024
#define EE 512
#define HH 8
#define DD 64
#define NROWS (BB*LL)   // 2048
#define QT 8
#define KSPLIT 4
#define KRANGE (LL/KSPLIT)  // 256

typedef __attribute__((ext_vector_type(4))) float f32x4;
typedef __attribute__((ext_vector_type(2))) float f32x2;
typedef __attribute__((ext_vector_type(8))) short short8;

static __device__ __forceinline__ short to_bf16(float f) {
    __bf16 h = (__bf16)f;
    return __builtin_bit_cast(short, h);
}

// -------- shared MFMA GEMM core: acc += X[64-tile] @ W[64-tile]^T (bf16) --------
__device__ __forceinline__ void gemm_core(const float* __restrict__ X,
                                          const float* __restrict__ W,
                                          short* As, short* Bs,
                                          int m0, int n0, f32x4 (&acc)[2][2])
{
    const int tid  = threadIdx.x;
    const int lane = tid & 63, wave = tid >> 6;
    const int wr = wave >> 1, wc = wave & 1;
    const int r = tid >> 2, cq = tid & 3;
    const float* ax = X + (size_t)(m0 + r) * EE + cq * 8;
    const float* bx = W + (size_t)(n0 + r) * EE + cq * 8;

    float a_reg[8], b_reg[8];
    #pragma unroll
    for (int j = 0; j < 8; ++j) { a_reg[j] = ax[j]; b_reg[j] = bx[j]; }

    short* apos = &As[r * 32 + ((cq ^ (r & 3)) * 8)];
    short* bpos = &Bs[r * 32 + ((cq ^ (r & 3)) * 8)];
    const int swz = ((lane >> 4) ^ (lane & 3)) * 8;

    for (int it = 0; it < 16; ++it) {
        short8 av, bv;
        #pragma unroll
        for (int j = 0; j < 8; ++j) { av[j] = to_bf16(a_reg[j]); bv[j] = to_bf16(b_reg[j]); }
        __syncthreads();
        *reinterpret_cast<short8*>(apos) = av;
        *reinterpret_cast<short8*>(bpos) = bv;
        __syncthreads();
        if (it < 15) {
            const float* axn = ax + (it + 1) * 32;
            const float* bxn = bx + (it + 1) * 32;
            #pragma unroll
            for (int j = 0; j < 8; ++j) { a_reg[j] = axn[j]; b_reg[j] = bxn[j]; }
        }
        short8 af[2], bf[2];
        #pragma unroll
        for (int mi = 0; mi < 2; ++mi) {
            int row = wr * 32 + mi * 16 + (lane & 15);
            af[mi] = *reinterpret_cast<short8*>(&As[row * 32 + swz]);
        }
        #pragma unroll
        for (int ni = 0; ni < 2; ++ni) {
            int row = wc * 32 + ni * 16 + (lane & 15);
            bf[ni] = *reinterpret_cast<short8*>(&Bs[row * 32 + swz]);
        }
        #pragma unroll
        for (int mi = 0; mi < 2; ++mi)
            #pragma unroll
            for (int ni = 0; ni < 2; ++ni)
                acc[mi][ni] = __builtin_amdgcn_mfma_f32_16x16x32_bf16(af[mi], bf[ni], acc[mi][ni], 0, 0, 0);
    }
}

// -------- fused Q/K/V projections; z=0:Q(bf16) z=1:K(bf16) z=2:V(f32) --------
__global__ __launch_bounds__(256) void qkv_gemm(const float* __restrict__ q_in,
                                                const float* __restrict__ k_in,
                                                const float* __restrict__ v_in,
                                                const float* __restrict__ Wq,
                                                const float* __restrict__ Wk,
                                                const float* __restrict__ Wv,
                                                const float* __restrict__ bq,
                                                const float* __restrict__ bk,
                                                const float* __restrict__ bv,
                                                short* __restrict__ Qo,
                                                short* __restrict__ Ko,
                                                float* __restrict__ Vo)
{
    __shared__ short As[64 * 32];
    __shared__ short Bs[64 * 32];
    const int z = blockIdx.z;
    const float* X = (z == 0) ? q_in : (z == 1) ? k_in : v_in;
    const float* W = (z == 0) ? Wq : (z == 1) ? Wk : Wv;
    const float* bias = (z == 0) ? bq : (z == 1) ? bk : bv;

    const int m0 = blockIdx.x * 64, n0 = blockIdx.y * 64;
    f32x4 acc[2][2];
    #pragma unroll
    for (int mi = 0; mi < 2; ++mi)
        #pragma unroll
        for (int ni = 0; ni < 2; ++ni) acc[mi][ni] = (f32x4){0.f,0.f,0.f,0.f};

    gemm_core(X, W, As, Bs, m0, n0, acc);

    const int tid = threadIdx.x, lane = tid & 63, wave = tid >> 6;
    const int wr = wave >> 1, wc = wave & 1;
    const int col_l = lane & 15, rowg = (lane >> 4) * 4;
    #pragma unroll
    for (int mi = 0; mi < 2; ++mi)
        #pragma unroll
        for (int ni = 0; ni < 2; ++ni) {
            int colg = n0 + wc * 32 + ni * 16 + col_l;
            float bn = bias[colg];
            #pragma unroll
            for (int rr = 0; rr < 4; ++rr) {
                int mg = m0 + wr * 32 + mi * 16 + rowg + rr;
                float v = acc[mi][ni][rr] + bn;
                if (z == 2) Vo[(size_t)mg * EE + colg] = v;
                else {
                    short* ob = z ? Ko : Qo;
                    ob[(size_t)mg * EE + colg] = to_bf16(v);
                }
            }
        }
}

// -------- plain f32-out GEMM (final projection) --------
__global__ __launch_bounds__(256) void gemm_f32(const float* __restrict__ X,
                                                const float* __restrict__ W,
                                                const float* __restrict__ bias,
                                                float* __restrict__ out)
{
    __shared__ short As[64 * 32];
    __shared__ short Bs[64 * 32];
    const int m0 = blockIdx.x * 64, n0 = blockIdx.y * 64;
    f32x4 acc[2][2];
    #pragma unroll
    for (int mi = 0; mi < 2; ++mi)
        #pragma unroll
        for (int ni = 0; ni < 2; ++ni) acc[mi][ni] = (f32x4){0.f,0.f,0.f,0.f};

    gemm_core(X, W, As, Bs, m0, n0, acc);

    const int tid = threadIdx.x, lane = tid & 63, wave = tid >> 6;
    const int wr = wave >> 1, wc = wave & 1;
    const int col_l = lane & 15, rowg = (lane >> 4) * 4;
    #pragma unroll
    for (int mi = 0; mi < 2; ++mi)
        #pragma unroll
        for (int ni = 0; ni < 2; ++ni) {
            int colg = n0 + wc * 32 + ni * 16 + col_l;
            float bn = bias[colg];
            #pragma unroll
            for (int rr = 0; rr < 4; ++rr) {
                int mg = m0 + wr * 32 + mi * 16 + rowg + rr;
                out[(size_t)mg * EE + colg] = acc[mi][ni][rr] + bn;
            }
        }
}

// -------- fused attention --------
// Qb,Kb: bf16 [B*L][E]; V: f32 [B*L][E]; ATT: f32 accumulated via atomics.
// sw layout: [k(64)][h*8 + q], row stride 68 floats.
__global__ __launch_bounds__(256, 4) void attn3(const short* __restrict__ Qb,
                                                const short* __restrict__ Kb,
                                                const float* __restrict__ V,
                                                float* __restrict__ ATT)
{
    __shared__ short Qs[QT * EE];     // 8 KB, XOR-swizzled 8-elem chunks
    __shared__ float sw[64 * 68];     // 17.4 KB

    const int tid = threadIdx.x, lane = tid & 63, wave = tid >> 6;

    // XCD-aware decode: each XCD chunk owns one (b, k-quarter)
    const int fid = blockIdx.x;                    // 0..1023
    const int newid = (fid & 7) * 128 + (fid >> 3);
    const int b = newid >> 9;
    const int ksp = (newid >> 7) & 3;
    const int qpos = newid & 127;
    const int bq0 = b * LL + qpos * QT;
    const int k0base = ksp * KRANGE;

    // stage Q tile (bf16), XOR swizzle chunk c -> c^q
    for (int i = tid; i < QT * 64; i += 256) {
        int q = i >> 6, c = i & 63;
        short8 v = *reinterpret_cast<const short8*>(Qb + ((size_t)(bq0 + q) << 9) + c * 8);
        *reinterpret_cast<short8*>(&Qs[(q << 9) + ((c ^ q) << 3)]) = v;
    }

    f32x2 oacc[4][HH];
    #pragma unroll
    for (int qp = 0; qp < 4; ++qp)
        #pragma unroll
        for (int h = 0; h < HH; ++h) oacc[qp][h] = (f32x2){0.f, 0.f};

    const int qr = (lane & 15) & 7;
    const int kg4 = lane >> 4;

    for (int t = 0; t < KRANGE / 64; ++t) {
        const int k0 = k0base + t * 64;
        __syncthreads();   // sw free (prev phase 3 done); Qs ready (t==0)

        // ---- phase 1: MFMA scores S^T[k][q] for heads {wave, wave+4} ----
        const short* kbase = Kb + ((size_t)(b * LL + k0) << 9);
        #pragma unroll
        for (int hh = 0; hh < 2; ++hh) {
            const int h = wave + hh * 4;
            short8 bfq[2];
            #pragma unroll
            for (int kc = 0; kc < 2; ++kc) {
                int c = h * 8 + kc * 4 + kg4;
                bfq[kc] = *reinterpret_cast<const short8*>(&Qs[(qr << 9) + ((c ^ qr) << 3)]);
            }
            f32x4 acc[4];
            #pragma unroll
            for (int m = 0; m < 4; ++m) acc[m] = (f32x4){0.f,0.f,0.f,0.f};
            #pragma unroll
            for (int m = 0; m < 4; ++m) {
                const short* arow = kbase + ((size_t)(m * 16 + (lane & 15)) << 9) + (h << 6) + (kg4 << 3);
                short8 af0 = *reinterpret_cast<const short8*>(arow);
                short8 af1 = *reinterpret_cast<const short8*>(arow + 32);
                acc[m] = __builtin_amdgcn_mfma_f32_16x16x32_bf16(af0, bfq[0], acc[m], 0, 0, 0);
                acc[m] = __builtin_amdgcn_mfma_f32_16x16x32_bf16(af1, bfq[1], acc[m], 0, 0, 0);
            }
            if ((lane & 15) < 8) {
                int q = lane & 15;
                #pragma unroll
                for (int m = 0; m < 4; ++m)
                    #pragma unroll
                    for (int r = 0; r < 4; ++r) {
                        int k = m * 16 + kg4 * 4 + r;
                        sw[k * 68 + h * 8 + q] = acc[m][r] * 0.125f;
                    }
            }
        }
        __syncthreads();

        // ---- phase 2: RMS over heads, normalize in place ----
        #pragma unroll
        for (int rep = 0; rep < 2; ++rep) {
            int idx = rep * 256 + tid;
            int k = idx >> 3, q = idx & 7;
            float* sp = &sw[k * 68 + q];
            float s[HH], ss = 0.f;
            #pragma unroll
            for (int h = 0; h < HH; ++h) { s[h] = sp[h * 8]; ss += s[h] * s[h]; }
            float inv = rsqrtf(ss * 0.125f + 1e-8f);
            #pragma unroll
            for (int h = 0; h < HH; ++h) sp[h * 8] = s[h] * inv;
        }
        __syncthreads();

        // ---- phase 3: packed-f32 over q-pairs; lane = d ----
        for (int j = 0; j < 16; ++j) {
            int kl = j * 4 + wave;
            const float* vp = V + ((size_t)(b * LL + k0 + kl) << 9) + lane;
            float vr[HH];
            #pragma unroll
            for (int h = 0; h < HH; ++h) vr[h] = vp[h * DD];
            const float* swr = &sw[kl * 68];
            f32x2 xv[4];
            #pragma unroll
            for (int qp = 0; qp < 4; ++qp) xv[qp] = (f32x2){0.f, 0.f};
            #pragma unroll
            for (int h = 0; h < HH; ++h) {
                f32x4 wa = *reinterpret_cast<const f32x4*>(&swr[h * 8]);
                f32x4 wb = *reinterpret_cast<const f32x4*>(&swr[h * 8 + 4]);
                xv[0] += (f32x2){wa[0], wa[1]} * vr[h];
                xv[1] += (f32x2){wa[2], wa[3]} * vr[h];
                xv[2] += (f32x2){wb[0], wb[1]} * vr[h];
                xv[3] += (f32x2){wb[2], wb[3]} * vr[h];
            }
            #pragma unroll
            for (int qp = 0; qp < 4; ++qp) {
                xv[qp][0] = xv[qp][0] / (1.f + __expf(-xv[qp][0]));
                xv[qp][1] = xv[qp][1] / (1.f + __expf(-xv[qp][1]));
            }
            #pragma unroll
            for (int h = 0; h < HH; ++h) {
                f32x4 wa = *reinterpret_cast<const f32x4*>(&swr[h * 8]);
                f32x4 wb = *reinterpret_cast<const f32x4*>(&swr[h * 8 + 4]);
                oacc[0][h] += (f32x2){wa[0], wa[1]} * xv[0];
                oacc[1][h] += (f32x2){wa[2], wa[3]} * xv[1];
                oacc[2][h] += (f32x2){wb[0], wb[1]} * xv[2];
                oacc[3][h] += (f32x2){wb[2], wb[3]} * xv[3];
            }
        }
    }

    // ---- cross-wave reduce + global accumulate ----
    float* red = sw;
    for (int q = 0; q < QT; ++q) {
        __syncthreads();
        #pragma unroll
        for (int h = 0; h < HH; ++h)
            red[(wave * HH + h) * 64 + lane] = oacc[q >> 1][h][q & 1];
        __syncthreads();
        #pragma unroll
        for (int i2 = 0; i2 < 2; ++i2) {
            int e = tid + i2 * 256;
            float sum = red[e] + red[e + 512] + red[e + 1024] + red[e + 1536];
            atomicAdd(&ATT[(size_t)(bq0 + q) * EE + e], sum);
        }
    }
}

extern "C" void kernel_launch(void* const* d_in, const int* in_sizes, int n_in,
                              void* d_out, int out_size, void* d_ws, size_t ws_size,
                              hipStream_t stream) {
    const float* query = (const float*)d_in[0];
    const float* key   = (const float*)d_in[1];
    const float* value = (const float*)d_in[2];
    const float* Wq = (const float*)d_in[3];
    const float* biasq = (const float*)d_in[4];
    const float* Wk = (const float*)d_in[5];
    const float* biask = (const float*)d_in[6];
    const float* Wv = (const float*)d_in[7];
    const float* biasv = (const float*)d_in[8];
    const float* Wo = (const float*)d_in[9];
    const float* biaso = (const float*)d_in[10];
    float* out = (float*)d_out;

    char* wsb = (char*)d_ws;
    short* Qb  = (short*)(wsb);                    // 2 MB bf16
    short* Kb  = (short*)(wsb + (2u << 20));       // 2 MB bf16
    float* Vb  = (float*)(wsb + (4u << 20));       // 4 MB f32
    float* ATT = (float*)(wsb + (8u << 20));       // 4 MB f32

    hipMemsetAsync(ATT, 0, (size_t)NROWS * EE * sizeof(float), stream);

    dim3 gQKV(NROWS / 64, EE / 64, 3);
    qkv_gemm<<<gQKV, 256, 0, stream>>>(query, key, value, Wq, Wk, Wv,
                                       biasq, biask, biasv, Qb, Kb, Vb);

    attn3<<<dim3(NROWS / QT * KSPLIT, 1, 1), dim3(256, 1, 1), 0, stream>>>(Qb, Kb, Vb, ATT);

    gemm_f32<<<dim3(NROWS / 64, EE / 64, 1), 256, 0, stream>>>(ATT, Wo, biaso, out);
}